// Round 4
// baseline (287.245 us; speedup 1.0000x reference)
//
#include <hip/hip_runtime.h>
#include <stdint.h>

typedef int v4i __attribute__((ext_vector_type(4)));

#define AS1(p) ((const __attribute__((address_space(1))) void*)(p))
#define AS3(p) ((__attribute__((address_space(3))) void*)(p))

// ---------------- pack weight: int32 -> int8 ----------------
__global__ __launch_bounds__(256) void pack_w_kernel(
    const int* __restrict__ w, int8_t* __restrict__ w8, int n4)
{
    int t = blockIdx.x * 256 + threadIdx.x;
    if (t >= n4) return;
    int4 v = ((const int4*)w)[t];
    ((int*)w8)[t] = (v.x & 255) | ((v.y & 255) << 8) |
                    ((v.z & 255) << 16) | ((v.w & 255) << 24);
}

// ---------------- fused quant + int8 GEMM ----------------
// BM=32 x BN=1024 x BK=64, 8 waves. ALL global traffic is global_load_lds
// (uniform vmcnt stream). A path: fp32 tile DMA -> LDS -> ds_read (own lane's
// chunk) -> quant VALU -> swizzled ds_write int8. Every op guarded by a
// counted vmcnt is a MEMORY op (cannot hoist across asm "memory" clobbers) --
// no register-only consumer of an opaque load exists (rule #18 safe).
#define GM 65536
#define GN 1024
#define GK 1024
#define NT 16

__global__ __launch_bounds__(512, 2) void fused_kernel(
    const float* __restrict__ X,    // [GM][GK] fp32
    const int8_t* __restrict__ B8,  // [GN][GK] int8
    const int* __restrict__ bias,
    const float* __restrict__ isc_p, const int* __restrict__ izp_p,
    const float* __restrict__ osc_p, const int* __restrict__ ozp_p,
    float* __restrict__ out)
{
    __shared__ int8_t Bsb[2][65536];  // 128 KB: 1024 rows x 64 B, XOR-swizzled slots
    __shared__ float  A32[2][2048];   //  16 KB: 32 rows x 64 fp32, linear (lane-local)
    __shared__ int8_t Asb[2][2048];   //   4 KB: 32 rows x 64 B, XOR-swizzled slots

    const int tid = threadIdx.x;          // 0..511
    const int w   = tid >> 6, l = tid & 63;
    const int r15 = l & 15,  s4 = l >> 4;
    const int bm0 = blockIdx.x << 5;      // 32 M-rows per block, grid 2048

    // in-loop scalars: load once, launder so no reload can appear in the loop
    float isc_r = *isc_p;
    float izp_r = (float)(*izp_p);
    float isc, izp;
    asm volatile("v_mov_b32 %0, %1" : "=v"(isc) : "v"(isc_r));
    asm volatile("v_mov_b32 %0, %1" : "=v"(izp) : "v"(izp_r));
    asm volatile("s_waitcnt vmcnt(0) lgkmcnt(0)" ::: "memory");

    // B staging: wave w stages rows w*128..w*128+127 (wave-local). Linear DMA
    // dest; slot-swizzle (slot ^= (row>>1)&3) applied on the GLOBAL source col.
    const int8_t* b_base = B8 + (size_t)(w * 128 + (l >> 2)) * GK
                              + ((((l & 3) ^ ((l >> 3) & 3))) << 4);

    // A32 staging: wave w stages 1 KB; lane l writes bytes [tid*16, tid*16+16)
    // = floats [tid*4, tid*4+4) -> row w*4+(l>>4), float col (l&15)*4.
    const float* a32_src = X + (size_t)(bm0 + w * 4 + (l >> 4)) * GK + ((l & 15) << 2);

    // quant: thread reads its OWN 4 floats (written by its own DMA lane slot),
    // writes 4 int8 at logical (row=tid>>4, col=(tid&15)*4), slot-swizzled.
    const int a_dst = ((tid >> 4) << 6)
                    + ((((tid >> 2) & 3) ^ ((tid >> 5) & 3)) << 4)
                    + ((tid & 3) << 2);

    // fragment read offsets (same XOR on read; key reduces to (r15>>1)&3)
    int a_off[2], b_off[8];
#pragma unroll
    for (int i = 0; i < 2; ++i)
        a_off[i] = ((i * 16 + r15) << 6) + ((s4 ^ ((r15 >> 1) & 3)) << 4);
#pragma unroll
    for (int j = 0; j < 8; ++j)
        b_off[j] = ((w * 128 + j * 16 + r15) << 6) + ((s4 ^ ((r15 >> 1) & 3)) << 4);

    v4i acc[2][8];
#pragma unroll
    for (int i = 0; i < 2; ++i)
#pragma unroll
        for (int j = 0; j < 8; ++j) acc[i][j] = (v4i){0, 0, 0, 0};

#define STAGE_B(T, BUF) do { \
    _Pragma("unroll") \
    for (int c = 0; c < 8; ++c) \
        __builtin_amdgcn_global_load_lds( \
            AS1(b_base + ((size_t)(c) << 14) + (T) * 64), \
            AS3(&Bsb[BUF][(w * 8 + c) << 10]), 16, 0, 0); \
} while (0)

#define STAGE_A(T, BUF) \
    __builtin_amdgcn_global_load_lds(AS1(a32_src + (T) * 64), \
                                     AS3(&A32[BUF][w << 8]), 16, 0, 0)

#define QUANT(BUF) do { \
    float4 v_ = *(const float4*)&A32[BUF][tid << 2]; \
    float q0 = fminf(127.f, fmaxf(-128.f, rintf(v_.x / isc) + izp)); \
    float q1 = fminf(127.f, fmaxf(-128.f, rintf(v_.y / isc) + izp)); \
    float q2 = fminf(127.f, fmaxf(-128.f, rintf(v_.z / isc) + izp)); \
    float q3 = fminf(127.f, fmaxf(-128.f, rintf(v_.w / isc) + izp)); \
    int wd_ = ((int)q0 & 255) | (((int)q1 & 255) << 8) | \
              (((int)q2 & 255) << 16) | (((int)q3 & 255) << 24); \
    *(int*)&Asb[BUF][a_dst] = wd_; \
} while (0)

#define COMPUTE(BUF) do { \
    v4i af0 = *(const v4i*)&Asb[BUF][a_off[0]]; \
    v4i af1 = *(const v4i*)&Asb[BUF][a_off[1]]; \
    __builtin_amdgcn_s_setprio(1); \
    _Pragma("unroll") \
    for (int j = 0; j < 8; ++j) { \
        v4i bf = *(const v4i*)&Bsb[BUF][b_off[j]]; \
        acc[0][j] = __builtin_amdgcn_mfma_i32_16x16x64_i8(af0, bf, acc[0][j], 0, 0, 0); \
        acc[1][j] = __builtin_amdgcn_mfma_i32_16x16x64_i8(af1, bf, acc[1][j], 0, 0, 0); \
    } \
    __builtin_amdgcn_s_setprio(0); \
} while (0)

#define BAR() do { \
    asm volatile("s_waitcnt lgkmcnt(0)" ::: "memory"); \
    __builtin_amdgcn_s_barrier(); \
    __builtin_amdgcn_sched_barrier(0); \
} while (0)

    // Prologue: A32(0), B(0), A32(1) -> 10 outstanding.
    STAGE_A(0, 0);
    STAGE_B(0, 0);
    STAGE_A(1, 1);
    asm volatile("s_waitcnt vmcnt(9)" ::: "memory");   // A32(0) landed
    QUANT(0);                                          // tile 0 -> Asb[0]
    asm volatile("s_waitcnt vmcnt(1)" ::: "memory");   // B(0) landed; A32(1) in flight
    BAR();

    // Iter T: entry invariant = 1 outstanding (A32(T+1)).
#pragma unroll 1
    for (int t = 0; t < NT - 2; ++t) {
        STAGE_B(t + 1, (t + 1) & 1);          // +8 -> 9
        STAGE_A(t + 2, t & 1);                // +1 -> 10
        COMPUTE(t & 1);                       // tile t
        asm volatile("s_waitcnt vmcnt(9)" ::: "memory");  // A32(t+1) landed
        QUANT((t + 1) & 1);                   // tile t+1 -> Asb[(t+1)&1]
        asm volatile("s_waitcnt vmcnt(1)" ::: "memory");  // B(t+1) landed
        BAR();
    }

    // T=14: entry 1 outstanding (A32(15)); no A32(16).
    STAGE_B(15, 1);                           // -> 9
    COMPUTE(0);                               // tile 14
    asm volatile("s_waitcnt vmcnt(8)" ::: "memory");      // A32(15) landed
    QUANT(1);                                 // tile 15 -> Asb[1]
    asm volatile("s_waitcnt vmcnt(0)" ::: "memory");      // B(15) landed
    BAR();
    COMPUTE(1);                               // tile 15

#undef STAGE_B
#undef STAGE_A
#undef QUANT
#undef COMPUTE
#undef BAR

    // epilogue (loads here are after the counted region)
    const float osc = *osc_p;
    const int   ozp = *ozp_p;
    int bj[8];
#pragma unroll
    for (int j = 0; j < 8; ++j)
        bj[j] = bias[w * 128 + j * 16 + r15] - ozp;

    // C/D layout (16x16): col = l&15, row = (l>>4)*4 + reg
#pragma unroll
    for (int i = 0; i < 2; ++i) {
        const int mrow = bm0 + i * 16 + s4 * 4;
#pragma unroll
        for (int j = 0; j < 8; ++j) {
            const int n = w * 128 + j * 16 + r15;
            float* op = out + (size_t)mrow * GN + n;
#pragma unroll
            for (int r = 0; r < 4; ++r)
                __builtin_nontemporal_store((float)(acc[i][j][r] + bj[j]) * osc,
                                            op + (size_t)r * GN);
        }
    }
}

extern "C" void kernel_launch(void* const* d_in, const int* in_sizes, int n_in,
                              void* d_out, int out_size, void* d_ws, size_t ws_size,
                              hipStream_t stream)
{
    const float* x         = (const float*)d_in[0];
    const int*   w_int     = (const int*)d_in[1];
    const int*   b_int     = (const int*)d_in[2];
    const float* in_scale  = (const float*)d_in[3];
    const float* out_scale = (const float*)d_in[4];
    const int*   izp       = (const int*)d_in[5];
    const int*   ozp       = (const int*)d_in[6];
    float* out = (float*)d_out;

    int8_t* w8 = (int8_t*)d_ws;   // 1 MB packed weight

    pack_w_kernel<<<1024, 256, 0, stream>>>(w_int, w8, 262144);
    fused_kernel<<<2048, 512, 0, stream>>>(x, w8, b_int,
                                           in_scale, izp, out_scale, ozp, out);
}

// Round 5
// 156.713 us; speedup vs baseline: 1.8329x; 1.8329x over previous
//
#include <hip/hip_runtime.h>
#include <stdint.h>

typedef int v4i __attribute__((ext_vector_type(4)));

#define AS1(p) ((const __attribute__((address_space(1))) void*)(p))
#define AS3(p) ((__attribute__((address_space(3))) void*)(p))

// ---------------- quantize x: fp32 -> int8 ----------------
__global__ __launch_bounds__(256) void quant_x_kernel(
    const float* __restrict__ x, int8_t* __restrict__ xq,
    const float* __restrict__ s_p, const int* __restrict__ izp_p, int n16)
{
    int t = blockIdx.x * 256 + threadIdx.x;
    if (t >= n16) return;
    float s = *s_p;
    float zp = (float)(*izp_p);
    const float4* xin = (const float4*)x + (size_t)t * 4;
    int words[4];
#pragma unroll
    for (int i = 0; i < 4; ++i) {
        float4 v = xin[i];
        // round-half-even like jnp.round; exact IEEE division like the reference
        float q0 = fminf(127.f, fmaxf(-128.f, rintf(v.x / s) + zp));
        float q1 = fminf(127.f, fmaxf(-128.f, rintf(v.y / s) + zp));
        float q2 = fminf(127.f, fmaxf(-128.f, rintf(v.z / s) + zp));
        float q3 = fminf(127.f, fmaxf(-128.f, rintf(v.w / s) + zp));
        words[i] = ((int)q0 & 255) | (((int)q1 & 255) << 8) |
                   (((int)q2 & 255) << 16) | (((int)q3 & 255) << 24);
    }
    ((int4*)xq)[t] = make_int4(words[0], words[1], words[2], words[3]);
}

// ---------------- pack weight: int32 -> int8 ----------------
__global__ __launch_bounds__(256) void pack_w_kernel(
    const int* __restrict__ w, int8_t* __restrict__ w8, int n4)
{
    int t = blockIdx.x * 256 + threadIdx.x;
    if (t >= n4) return;
    int4 v = ((const int4*)w)[t];
    ((int*)w8)[t] = (v.x & 255) | ((v.y & 255) << 8) |
                    ((v.z & 255) << 16) | ((v.w & 255) << 24);
}

// ---------------- int8 GEMM: 128x128 tile, 4 waves, 3-deep ring, counted vmcnt
#define GM 65536
#define GN 1024
#define GK 1024
#define NT 16   // K-tiles of 64

__global__ __launch_bounds__(256, 3) void gemm_i8_kernel(
    const int8_t* __restrict__ A,   // [GM][GK]
    const int8_t* __restrict__ B,   // [GN][GK]
    const int* __restrict__ bias,
    const float* __restrict__ osc_p, const int* __restrict__ ozp_p,
    float* __restrict__ out)
{
    // 3-deep ring: [buf][A/B][128 rows x 64 B], XOR slot-swizzle (slot ^= (row>>1)&3)
    __shared__ int8_t lds[3][2][8192];   // 48 KB -> 3 blocks/CU

    const int tid = threadIdx.x;
    const int w = tid >> 6, l = tid & 63;
    const int wr = w >> 1, wc = w & 1;           // 2x2 wave grid, per-wave 64x64
    const int r15 = l & 15, s4 = l >> 4;

    // XCD-bijective: grid 4096 = 8 XCD chunks x 512. Within a chunk, 8 consecutive
    // logical blocks share one bm-panel (A panel L2-resident) and cover all bn
    // (B is 1 MB -> L2-resident per XCD).
    const int wg = blockIdx.x;
    const int lg = ((wg & 7) << 9) + (wg >> 3);
    const int bm0 = (lg >> 3) << 7;
    const int bn0 = (lg & 7) << 7;

    // Staging: per thread 2 A + 2 B loads (16 B each) per K-tile. LDS dest linear
    // (wave-uniform base + lane*16); swizzle applied on the GLOBAL source col.
    const int8_t* a_src[2];
    const int8_t* b_src[2];
    int st_dst[2];
#pragma unroll
    for (int e = 0; e < 2; ++e) {
        int o = e * 4096 + tid * 16;             // linear LDS offset in 8 KB matrix buf
        int row = o >> 6;                        // 0..127
        int slot = (o >> 4) & 3;
        int gcol = ((slot ^ ((row >> 1) & 3)) << 4);
        a_src[e] = A + (size_t)(bm0 + row) * GK + gcol;
        b_src[e] = B + (size_t)(bn0 + row) * GK + gcol;
        st_dst[e] = e * 4096 + w * 1024;         // wave-uniform
    }

    // Fragment read offsets (same XOR on read)
    int a_off[4], b_off[4];
#pragma unroll
    for (int i = 0; i < 4; ++i) {
        int row = wr * 64 + i * 16 + r15;
        a_off[i] = (row << 6) + ((s4 ^ ((row >> 1) & 3)) << 4);
    }
#pragma unroll
    for (int j = 0; j < 4; ++j) {
        int row = wc * 64 + j * 16 + r15;
        b_off[j] = (row << 6) + ((s4 ^ ((row >> 1) & 3)) << 4);
    }

    v4i acc[4][4];
#pragma unroll
    for (int i = 0; i < 4; ++i)
#pragma unroll
        for (int j = 0; j < 4; ++j) acc[i][j] = (v4i){0, 0, 0, 0};

#define STAGE(T, BUF) do { \
    __builtin_amdgcn_global_load_lds(AS1(a_src[0] + (T) * 64), AS3(&lds[BUF][0][st_dst[0]]), 16, 0, 0); \
    __builtin_amdgcn_global_load_lds(AS1(a_src[1] + (T) * 64), AS3(&lds[BUF][0][st_dst[1]]), 16, 0, 0); \
    __builtin_amdgcn_global_load_lds(AS1(b_src[0] + (T) * 64), AS3(&lds[BUF][1][st_dst[0]]), 16, 0, 0); \
    __builtin_amdgcn_global_load_lds(AS1(b_src[1] + (T) * 64), AS3(&lds[BUF][1][st_dst[1]]), 16, 0, 0); \
} while (0)

#define COMPUTE(BUF) do { \
    v4i af[4], bf[4]; \
    _Pragma("unroll") \
    for (int j = 0; j < 4; ++j) bf[j] = *(const v4i*)&lds[BUF][1][b_off[j]]; \
    _Pragma("unroll") \
    for (int i = 0; i < 4; ++i) af[i] = *(const v4i*)&lds[BUF][0][a_off[i]]; \
    __builtin_amdgcn_s_setprio(1); \
    _Pragma("unroll") \
    for (int i = 0; i < 4; ++i) \
    _Pragma("unroll") \
        for (int j = 0; j < 4; ++j) \
            acc[i][j] = __builtin_amdgcn_mfma_i32_16x16x64_i8(af[i], bf[j], acc[i][j], 0, 0, 0); \
    __builtin_amdgcn_s_setprio(0); \
} while (0)

    // Prologue: prefetch tiles 0,1 (8 loads/wave in flight)
    STAGE(0, 0);
    STAGE(1, 1);

    // Iter t: vmcnt(4) = tile t landed (t+1 in flight); barrier also guarantees
    // no wave still reads buf (t+2)%3 (its tile t-1 reads finished before the
    // PREVIOUS barrier). Stage t+2, compute t. Never drain to 0 mid-loop.
    int c0 = 0, c1 = 1, c2 = 2;
#pragma unroll 1
    for (int t = 0; t < NT - 2; ++t) {
        asm volatile("s_waitcnt vmcnt(4)" ::: "memory");
        __builtin_amdgcn_s_barrier();
        STAGE(t + 2, c2);
        COMPUTE(c0);
        int tmp = c0; c0 = c1; c1 = c2; c2 = tmp;   // rotate ring
    }
    // Tail: tiles 14,15
    asm volatile("s_waitcnt vmcnt(4)" ::: "memory");
    __builtin_amdgcn_s_barrier();
    COMPUTE(c0);
    asm volatile("s_waitcnt vmcnt(0)" ::: "memory");
    __builtin_amdgcn_s_barrier();
    COMPUTE(c1);

#undef STAGE
#undef COMPUTE

    const float osc = *osc_p;
    const int ozp = *ozp_p;
    int bj[4];
#pragma unroll
    for (int j = 0; j < 4; ++j)
        bj[j] = bias[bn0 + wc * 64 + j * 16 + r15] - ozp;

    // C/D layout (16x16): col = l&15, row = (l>>4)*4 + reg
#pragma unroll
    for (int i = 0; i < 4; ++i) {
        const int mrow = bm0 + wr * 64 + i * 16 + s4 * 4;
#pragma unroll
        for (int j = 0; j < 4; ++j) {
            const int n = bn0 + wc * 64 + j * 16 + r15;
            float* op = out + (size_t)mrow * GN + n;
#pragma unroll
            for (int r = 0; r < 4; ++r)
                __builtin_nontemporal_store((float)(acc[i][j][r] + bj[j]) * osc,
                                            op + (size_t)r * GN);
        }
    }
}

extern "C" void kernel_launch(void* const* d_in, const int* in_sizes, int n_in,
                              void* d_out, int out_size, void* d_ws, size_t ws_size,
                              hipStream_t stream)
{
    const float* x         = (const float*)d_in[0];
    const int*   w_int     = (const int*)d_in[1];
    const int*   b_int     = (const int*)d_in[2];
    const float* in_scale  = (const float*)d_in[3];
    const float* out_scale = (const float*)d_in[4];
    const int*   izp       = (const int*)d_in[5];
    const int*   ozp       = (const int*)d_in[6];
    float* out = (float*)d_out;

    int8_t* xq = (int8_t*)d_ws;                            // 64 MB
    int8_t* w8 = (int8_t*)d_ws + (size_t)64 * 1024 * 1024; // 1 MB

    quant_x_kernel<<<16384, 256, 0, stream>>>(x, xq, in_scale, izp, 4194304);
    pack_w_kernel<<<1024, 256, 0, stream>>>(w_int, w8, 262144);
    gemm_i8_kernel<<<4096, 256, 0, stream>>>(xq, w8, b_int, out_scale, ozp, out);
}